// Round 1
// baseline (195.193 us; speedup 1.0000x reference)
//
#include <hip/hip_runtime.h>

#define B_ 8
#define S_ 4096
#define D_ 128

typedef __attribute__((ext_vector_type(4))) float f32x4;
typedef __attribute__((ext_vector_type(8))) short s16x8;

__device__ __forceinline__ unsigned short f2bf(float f) {
    union { float f; unsigned u; } v; v.f = f;
    unsigned r = (v.u + 0x7fffu + ((v.u >> 16) & 1u)) >> 16;
    return (unsigned short)r;
}

__device__ __forceinline__ s16x8 load_cvt8(const float* p) {
    f32x4 a = *(const f32x4*)p;
    f32x4 b = *(const f32x4*)(p + 4);
    s16x8 r;
    r[0] = (short)f2bf(a[0]); r[1] = (short)f2bf(a[1]);
    r[2] = (short)f2bf(a[2]); r[3] = (short)f2bf(a[3]);
    r[4] = (short)f2bf(b[0]); r[5] = (short)f2bf(b[1]);
    r[6] = (short)f2bf(b[2]); r[7] = (short)f2bf(b[3]);
    return r;
}

// ---------------------------------------------------------------------------
// Kernel 1: q/k/v projections + layernorm(q,k), bf16 outputs, v transposed.
// Block: 256 threads (4 waves x 16 rows = 64 rows). Grid: B*S/64 = 512.
// ---------------------------------------------------------------------------
__global__ __launch_bounds__(256, 1) void proj_kernel(
    const float* __restrict__ x,  const float* __restrict__ Wq,
    const float* __restrict__ Wk, const float* __restrict__ Wv,
    const float* __restrict__ qn_w, const float* __restrict__ qn_b,
    const float* __restrict__ kn_w, const float* __restrict__ kn_b,
    unsigned short* __restrict__ qo, unsigned short* __restrict__ ko,
    unsigned short* __restrict__ vto)
{
    __shared__ unsigned short wlds[128 * 136];   // W tile, padded (2-way max)
    __shared__ unsigned short vstage[128 * 72];  // v transpose staging [h][i64]

    const int tid  = threadIdx.x;
    const int lane = tid & 63;
    const int wv   = tid >> 6;
    const int j    = lane & 15;
    const int g    = lane >> 4;

    const int b    = blockIdx.x >> 6;           // 64 blocks per batch
    const int sblk = (blockIdx.x & 63) * 64;
    const int srow = sblk + wv * 16;

    // A fragments: rows of x (row = srow + j), 8 consecutive d per lane slot
    const float* xrow = x + ((size_t)b * S_ + srow + j) * D_;
    s16x8 af[4];
#pragma unroll
    for (int kk = 0; kk < 4; ++kk) af[kk] = load_cvt8(xrow + kk * 32 + g * 8);

    const int wrow = tid >> 1;
    const int wcol = (tid & 1) * 64;

#pragma unroll 1
    for (int m = 0; m < 3; ++m) {
        const float* Wm = (m == 0) ? Wq : (m == 1) ? Wk : Wv;
        __syncthreads();
        // stage W (f32 -> bf16) into LDS
#pragma unroll
        for (int it = 0; it < 8; ++it) {
            int col = wcol + it * 8;
            *(s16x8*)&wlds[wrow * 136 + col] = load_cvt8(Wm + wrow * 128 + col);
        }
        __syncthreads();

        f32x4 acc[8];
#pragma unroll
        for (int ct = 0; ct < 8; ++ct) { f32x4 z = {0.f, 0.f, 0.f, 0.f}; acc[ct] = z; }
#pragma unroll
        for (int ct = 0; ct < 8; ++ct) {
#pragma unroll
            for (int kk = 0; kk < 4; ++kk) {
                s16x8 bf = *(const s16x8*)&wlds[(ct * 16 + j) * 136 + kk * 32 + g * 8];
                acc[ct] = __builtin_amdgcn_mfma_f32_16x16x32_bf16(af[kk], bf, acc[ct], 0, 0, 0);
            }
        }

        if (m < 2) {
            const float* lw = (m == 0) ? qn_w : kn_w;
            const float* lb = (m == 0) ? qn_b : kn_b;
            float sum[4], sq[4];
#pragma unroll
            for (int r = 0; r < 4; ++r) {
                float s1 = 0.f, s2 = 0.f;
#pragma unroll
                for (int ct = 0; ct < 8; ++ct) { float v = acc[ct][r]; s1 += v; s2 += v * v; }
#pragma unroll
                for (int msk = 1; msk < 16; msk <<= 1) {
                    s1 += __shfl_xor(s1, msk);
                    s2 += __shfl_xor(s2, msk);
                }
                sum[r] = s1; sq[r] = s2;
            }
            float gwv[8], gbv[8];
#pragma unroll
            for (int ct = 0; ct < 8; ++ct) { gwv[ct] = lw[ct * 16 + j]; gbv[ct] = lb[ct * 16 + j]; }
            unsigned short* dst = (m == 0) ? qo : ko;
            const float post = (m == 0) ? 0.08838834764831845f : 1.0f;  // fold 1/sqrt(D) into q
#pragma unroll
            for (int r = 0; r < 4; ++r) {
                float mean = sum[r] * (1.f / 128.f);
                float var  = sq[r] * (1.f / 128.f) - mean * mean;
                float rstd = rsqrtf(var + 1e-5f);
                size_t rowoff = ((size_t)b * S_ + sblk + wv * 16 + g * 4 + r) * D_;
#pragma unroll
                for (int ct = 0; ct < 8; ++ct) {
                    float val = ((acc[ct][r] - mean) * rstd * gwv[ct] + gbv[ct]) * post;
                    dst[rowoff + ct * 16 + j] = f2bf(val);
                }
            }
        } else {
            // v: transpose through LDS, write vt[b][h][s] contiguous in s
#pragma unroll
            for (int ct = 0; ct < 8; ++ct) {
#pragma unroll
                for (int r = 0; r < 4; ++r) {
                    vstage[(ct * 16 + j) * 72 + wv * 16 + g * 4 + r] = f2bf(acc[ct][r]);
                }
            }
            __syncthreads();
            int h  = tid >> 1;
            int cb = (tid & 1) * 32;
#pragma unroll
            for (int c = 0; c < 4; ++c) {
                *(s16x8*)(vto + ((size_t)b * D_ + h) * S_ + sblk + cb + c * 8) =
                    *(const s16x8*)&vstage[h * 72 + cb + c * 8];
            }
        }
    }
}

// ---------------------------------------------------------------------------
// Kernel 2: flash attention. 4 waves x 16 q-rows per block, KV tiles of 32.
// Grid: B * S/64 = 512 blocks, 256 threads.
// ---------------------------------------------------------------------------
__global__ __launch_bounds__(256, 1) void attn_kernel(
    const unsigned short* __restrict__ qb, const unsigned short* __restrict__ kb,
    const unsigned short* __restrict__ vtb, float* __restrict__ out)
{
    __shared__ unsigned short klds[32 * 136];   // K tile [32][128] padded
    __shared__ unsigned short vlds[128 * 40];   // Vt tile [128][32] padded

    const int tid  = threadIdx.x;
    const int lane = tid & 63;
    const int wv   = tid >> 6;
    const int j    = lane & 15;
    const int g    = lane >> 4;

    const int b  = blockIdx.x >> 6;
    const int s0 = (blockIdx.x & 63) * 64;

    // Q fragments (rows s0 + wv*16 + j), q pre-scaled by 1/sqrt(D)
    const unsigned short* qrow = qb + ((size_t)b * S_ + s0 + wv * 16 + j) * D_;
    s16x8 qf[4];
#pragma unroll
    for (int kk = 0; kk < 4; ++kk) qf[kk] = *(const s16x8*)(qrow + kk * 32 + g * 8);

    // staging: K tile 32x128 (16 elems/thread), Vt tile 128x32 (16 elems/thread)
    const unsigned short* kg = kb + ((size_t)b * S_) * D_ + (tid >> 3) * D_ + (tid & 7) * 8;
    const unsigned short* vg = vtb + ((size_t)b * D_ + (tid >> 1)) * S_ + (tid & 1) * 16;
    unsigned short* kd = &klds[(tid >> 3) * 136 + (tid & 7) * 8];
    unsigned short* vd = &vlds[(tid >> 1) * 40 + (tid & 1) * 16];

    f32x4 acc[8];
#pragma unroll
    for (int ht = 0; ht < 8; ++ht) { f32x4 z = {0.f, 0.f, 0.f, 0.f}; acc[ht] = z; }
    float m_run = -INFINITY, l_run = 0.f;

    s16x8 rk0 = *(const s16x8*)kg;
    s16x8 rk1 = *(const s16x8*)(kg + 64);
    s16x8 rv0 = *(const s16x8*)vg;
    s16x8 rv1 = *(const s16x8*)(vg + 8);

    for (int kt = 0; kt < S_ / 32; ++kt) {
        __syncthreads();                 // previous tile's compute done
        *(s16x8*)kd = rk0;
        *(s16x8*)(kd + 64) = rk1;
        *(s16x8*)vd = rv0;
        *(s16x8*)(vd + 8) = rv1;
        __syncthreads();
        if (kt + 1 < S_ / 32) {          // prefetch next tile into regs
            rk0 = *(const s16x8*)(kg + (size_t)(kt + 1) * 32 * D_);
            rk1 = *(const s16x8*)(kg + (size_t)(kt + 1) * 32 * D_ + 64);
            rv0 = *(const s16x8*)(vg + (kt + 1) * 32);
            rv1 = *(const s16x8*)(vg + (kt + 1) * 32 + 8);
        }

        // QK^T (swapped): sa = S^T rows 0-15, sb = rows 16-31 of this kv tile
        f32x4 sa = {0.f, 0.f, 0.f, 0.f}, sb = {0.f, 0.f, 0.f, 0.f};
#pragma unroll
        for (int kk = 0; kk < 4; ++kk) {
            s16x8 ka  = *(const s16x8*)&klds[j        * 136 + kk * 32 + g * 8];
            s16x8 kb2 = *(const s16x8*)&klds[(16 + j) * 136 + kk * 32 + g * 8];
            sa = __builtin_amdgcn_mfma_f32_16x16x32_bf16(ka,  qf[kk], sa, 0, 0, 0);
            sb = __builtin_amdgcn_mfma_f32_16x16x32_bf16(kb2, qf[kk], sb, 0, 0, 0);
        }
        // lane holds S^T[k_local = 4g+r][q=j] (sa: k 0-15, sb: k 16-31)

        float mt = fmaxf(fmaxf(fmaxf(sa[0], sa[1]), fmaxf(sa[2], sa[3])),
                         fmaxf(fmaxf(sb[0], sb[1]), fmaxf(sb[2], sb[3])));
        mt = fmaxf(mt, __shfl_xor(mt, 16));
        mt = fmaxf(mt, __shfl_xor(mt, 32));   // per-q (=j) max over 32 k

        if (__any(mt > m_run)) {
            float mnew = fmaxf(m_run, mt);
            float corr = __expf(m_run - mnew);   // -inf start -> 0
            l_run *= corr;
            float cr0 = __shfl(corr, g * 4 + 0);
            float cr1 = __shfl(corr, g * 4 + 1);
            float cr2 = __shfl(corr, g * 4 + 2);
            float cr3 = __shfl(corr, g * 4 + 3);
#pragma unroll
            for (int ht = 0; ht < 8; ++ht) {
                acc[ht][0] *= cr0; acc[ht][1] *= cr1;
                acc[ht][2] *= cr2; acc[ht][3] *= cr3;
            }
            m_run = mnew;
        }

        float pa[4], pb[4];
#pragma unroll
        for (int r = 0; r < 4; ++r) {
            pa[r] = __expf(sa[r] - m_run);
            pb[r] = __expf(sb[r] - m_run);
        }
        float ts = (pa[0] + pa[1]) + (pa[2] + pa[3]) + (pb[0] + pb[1]) + (pb[2] + pb[3]);
        ts += __shfl_xor(ts, 16);
        ts += __shfl_xor(ts, 32);
        l_run += ts;

        // rebuild P as A-fragment (slot (g,b) -> k_local = 8g+b) via bpermute
        unsigned pa01 = (unsigned)f2bf(pa[0]) | ((unsigned)f2bf(pa[1]) << 16);
        unsigned pa23 = (unsigned)f2bf(pa[2]) | ((unsigned)f2bf(pa[3]) << 16);
        unsigned pb01 = (unsigned)f2bf(pb[0]) | ((unsigned)f2bf(pb[1]) << 16);
        unsigned pb23 = (unsigned)f2bf(pb[2]) | ((unsigned)f2bf(pb[3]) << 16);
        int src1 = ((2 * g) & 3) * 16 + j;
        int src2 = ((2 * g + 1) & 3) * 16 + j;
        unsigned a1 = __shfl(pa01, src1), a2 = __shfl(pa23, src1);
        unsigned a3 = __shfl(pa01, src2), a4 = __shfl(pa23, src2);
        unsigned b1 = __shfl(pb01, src1), b2 = __shfl(pb23, src1);
        unsigned b3 = __shfl(pb01, src2), b4 = __shfl(pb23, src2);
        bool hi = (g >= 2);
        union { unsigned u[4]; s16x8 v; } pu;
        pu.u[0] = hi ? b1 : a1;
        pu.u[1] = hi ? b2 : a2;
        pu.u[2] = hi ? b3 : a3;
        pu.u[3] = hi ? b4 : a4;

#pragma unroll
        for (int ht = 0; ht < 8; ++ht) {
            s16x8 vf = *(const s16x8*)&vlds[(ht * 16 + j) * 40 + g * 8];
            acc[ht] = __builtin_amdgcn_mfma_f32_16x16x32_bf16(pu.v, vf, acc[ht], 0, 0, 0);
        }
    }

    float linv = 1.0f / l_run;   // per q=j
    float lr0 = __shfl(linv, g * 4 + 0);
    float lr1 = __shfl(linv, g * 4 + 1);
    float lr2 = __shfl(linv, g * 4 + 2);
    float lr3 = __shfl(linv, g * 4 + 3);
#pragma unroll
    for (int ht = 0; ht < 8; ++ht) {
        size_t base = ((size_t)b * S_ + s0 + wv * 16 + g * 4) * D_ + ht * 16 + j;
        out[base         ] = acc[ht][0] * lr0;
        out[base +     D_] = acc[ht][1] * lr1;
        out[base + 2 * D_] = acc[ht][2] * lr2;
        out[base + 3 * D_] = acc[ht][3] * lr3;
    }
}

extern "C" void kernel_launch(void* const* d_in, const int* in_sizes, int n_in,
                              void* d_out, int out_size, void* d_ws, size_t ws_size,
                              hipStream_t stream) {
    const float* x    = (const float*)d_in[0];
    const float* Wq   = (const float*)d_in[1];
    const float* Wk   = (const float*)d_in[2];
    const float* Wv   = (const float*)d_in[3];
    const float* qn_w = (const float*)d_in[4];
    const float* qn_b = (const float*)d_in[5];
    const float* kn_w = (const float*)d_in[6];
    const float* kn_b = (const float*)d_in[7];
    float* out = (float*)d_out;

    const size_t n = (size_t)B_ * S_ * D_;   // 4,194,304
    unsigned short* qws  = (unsigned short*)d_ws;
    unsigned short* kws  = qws + n;
    unsigned short* vtws = kws + n;

    proj_kernel<<<512, 256, 0, stream>>>(x, Wq, Wk, Wv, qn_w, qn_b, kn_w, kn_b,
                                         qws, kws, vtws);
    attn_kernel<<<512, 256, 0, stream>>>(qws, kws, vtws, out);
}

// Round 2
// 159.821 us; speedup vs baseline: 1.2213x; 1.2213x over previous
//
#include <hip/hip_runtime.h>

#define B_ 8
#define S_ 4096
#define D_ 128
#define KVB 64
#define NT (S_ / KVB)

typedef __attribute__((ext_vector_type(4))) float f32x4;
typedef __attribute__((ext_vector_type(8))) short s16x8;

__device__ __forceinline__ unsigned short f2bf(float f) {
    union { float f; unsigned u; } v; v.f = f;
    unsigned r = (v.u + 0x7fffu + ((v.u >> 16) & 1u)) >> 16;
    return (unsigned short)r;
}

// round-half-up pack of two f32 -> (bf16 lo | bf16 hi<<16); cheap, |err| <= 2^-9 rel
__device__ __forceinline__ unsigned pack2(float lo, float hi) {
    union { float f; unsigned u; } a, b; a.f = lo; b.f = hi;
    return ((a.u + 0x8000u) >> 16) | ((b.u + 0x8000u) & 0xffff0000u);
}

__device__ __forceinline__ s16x8 load_cvt8(const float* p) {
    f32x4 a = *(const f32x4*)p;
    f32x4 b = *(const f32x4*)(p + 4);
    s16x8 r;
    r[0] = (short)f2bf(a[0]); r[1] = (short)f2bf(a[1]);
    r[2] = (short)f2bf(a[2]); r[3] = (short)f2bf(a[3]);
    r[4] = (short)f2bf(b[0]); r[5] = (short)f2bf(b[1]);
    r[6] = (short)f2bf(b[2]); r[7] = (short)f2bf(b[3]);
    return r;
}

// async global->LDS, 16B per lane. lds must be wave-uniform base; HW adds lane*16.
__device__ __forceinline__ void gld16(unsigned short* lds, const unsigned short* g) {
    __builtin_amdgcn_global_load_lds(
        (const __attribute__((address_space(1))) unsigned int*)g,
        (__attribute__((address_space(3))) unsigned int*)lds,
        16, 0, 0);
}

// ---------------------------------------------------------------------------
// Kernel 1: q/k/v projections + layernorm(q,k), bf16 outputs, v transposed.
// (unchanged from round 1 — ~4 us, not the bottleneck)
// ---------------------------------------------------------------------------
__global__ __launch_bounds__(256, 1) void proj_kernel(
    const float* __restrict__ x,  const float* __restrict__ Wq,
    const float* __restrict__ Wk, const float* __restrict__ Wv,
    const float* __restrict__ qn_w, const float* __restrict__ qn_b,
    const float* __restrict__ kn_w, const float* __restrict__ kn_b,
    unsigned short* __restrict__ qo, unsigned short* __restrict__ ko,
    unsigned short* __restrict__ vto)
{
    __shared__ unsigned short wlds[128 * 136];
    __shared__ unsigned short vstage[128 * 72];

    const int tid  = threadIdx.x;
    const int lane = tid & 63;
    const int wv   = tid >> 6;
    const int j    = lane & 15;
    const int g    = lane >> 4;

    const int b    = blockIdx.x >> 6;
    const int sblk = (blockIdx.x & 63) * 64;
    const int srow = sblk + wv * 16;

    const float* xrow = x + ((size_t)b * S_ + srow + j) * D_;
    s16x8 af[4];
#pragma unroll
    for (int kk = 0; kk < 4; ++kk) af[kk] = load_cvt8(xrow + kk * 32 + g * 8);

    const int wrow = tid >> 1;
    const int wcol = (tid & 1) * 64;

#pragma unroll 1
    for (int m = 0; m < 3; ++m) {
        const float* Wm = (m == 0) ? Wq : (m == 1) ? Wk : Wv;
        __syncthreads();
#pragma unroll
        for (int it = 0; it < 8; ++it) {
            int col = wcol + it * 8;
            *(s16x8*)&wlds[wrow * 136 + col] = load_cvt8(Wm + wrow * 128 + col);
        }
        __syncthreads();

        f32x4 acc[8];
#pragma unroll
        for (int ct = 0; ct < 8; ++ct) { f32x4 z = {0.f, 0.f, 0.f, 0.f}; acc[ct] = z; }
#pragma unroll
        for (int ct = 0; ct < 8; ++ct) {
#pragma unroll
            for (int kk = 0; kk < 4; ++kk) {
                s16x8 bf = *(const s16x8*)&wlds[(ct * 16 + j) * 136 + kk * 32 + g * 8];
                acc[ct] = __builtin_amdgcn_mfma_f32_16x16x32_bf16(af[kk], bf, acc[ct], 0, 0, 0);
            }
        }

        if (m < 2) {
            const float* lw = (m == 0) ? qn_w : kn_w;
            const float* lb = (m == 0) ? qn_b : kn_b;
            float sum[4], sq[4];
#pragma unroll
            for (int r = 0; r < 4; ++r) {
                float s1 = 0.f, s2 = 0.f;
#pragma unroll
                for (int ct = 0; ct < 8; ++ct) { float v = acc[ct][r]; s1 += v; s2 += v * v; }
#pragma unroll
                for (int msk = 1; msk < 16; msk <<= 1) {
                    s1 += __shfl_xor(s1, msk);
                    s2 += __shfl_xor(s2, msk);
                }
                sum[r] = s1; sq[r] = s2;
            }
            float gwv[8], gbv[8];
#pragma unroll
            for (int ct = 0; ct < 8; ++ct) { gwv[ct] = lw[ct * 16 + j]; gbv[ct] = lb[ct * 16 + j]; }
            unsigned short* dst = (m == 0) ? qo : ko;
            const float post = (m == 0) ? 0.08838834764831845f : 1.0f;
#pragma unroll
            for (int r = 0; r < 4; ++r) {
                float mean = sum[r] * (1.f / 128.f);
                float var  = sq[r] * (1.f / 128.f) - mean * mean;
                float rstd = rsqrtf(var + 1e-5f);
                size_t rowoff = ((size_t)b * S_ + sblk + wv * 16 + g * 4 + r) * D_;
#pragma unroll
                for (int ct = 0; ct < 8; ++ct) {
                    float val = ((acc[ct][r] - mean) * rstd * gwv[ct] + gbv[ct]) * post;
                    dst[rowoff + ct * 16 + j] = f2bf(val);
                }
            }
        } else {
#pragma unroll
            for (int ct = 0; ct < 8; ++ct) {
#pragma unroll
                for (int r = 0; r < 4; ++r) {
                    vstage[(ct * 16 + j) * 72 + wv * 16 + g * 4 + r] = f2bf(acc[ct][r]);
                }
            }
            __syncthreads();
            int h  = tid >> 1;
            int cb = (tid & 1) * 32;
#pragma unroll
            for (int c = 0; c < 4; ++c) {
                *(s16x8*)(vto + ((size_t)b * D_ + h) * S_ + sblk + cb + c * 8) =
                    *(const s16x8*)&vstage[h * 72 + cb + c * 8];
            }
        }
    }
}

// ---------------------------------------------------------------------------
// Kernel 2: flash attention. 4 waves x 16 q-rows, KVB=64, double-buffered
// XOR-swizzled LDS staged via global_load_lds, counted vmcnt, defer-max.
// Grid: B * S/64 = 512 blocks, 256 threads. LDS = 64 KiB -> 2 blocks/CU.
// ---------------------------------------------------------------------------
__global__ __launch_bounds__(256, 1) void attn_kernel(
    const unsigned short* __restrict__ qb, const unsigned short* __restrict__ kb,
    const unsigned short* __restrict__ vtb, float* __restrict__ out)
{
    // K tile: [64 k][128 d] bf16, 256B rows, 16B slot s stores cols (s^(row&7))*8..+8
    // V tile: [128 h][64 s] bf16, 128B rows, 16B slot s stores cols (s^(row&7))*8..+8
    __shared__ unsigned short kbuf[2][KVB * D_];
    __shared__ unsigned short vbuf[2][D_ * KVB];

    const int tid  = threadIdx.x;
    const int lane = tid & 63;
    const int wv   = tid >> 6;
    const int j    = lane & 15;
    const int g    = lane >> 4;

    const int b  = blockIdx.x >> 6;
    const int s0 = (blockIdx.x & 63) * 64;

    // Q fragments (rows s0 + wv*16 + j), q pre-scaled by 1/sqrt(D)
    const unsigned short* qrow = qb + ((size_t)b * S_ + s0 + wv * 16 + j) * D_;
    s16x8 qf[4];
#pragma unroll
    for (int kk = 0; kk < 4; ++kk) qf[kk] = *(const s16x8*)(qrow + kk * 32 + g * 8);

    const unsigned short* kg_base = kb  + (size_t)b * S_ * D_;
    const unsigned short* vg_base = vtb + (size_t)b * D_ * S_;

    // stage tile kt into buffer bi: 8 global_load_lds per thread (4 K + 4 V)
    auto STAGE = [&](int bi, int kt) {
        const int kv0 = kt * KVB;
#pragma unroll
        for (int it = 0; it < 4; ++it) {
            const int row = wv * 16 + it * 4 + (lane >> 4);
            const unsigned short* src =
                kg_base + (size_t)(kv0 + row) * D_ + (((lane & 15) ^ (row & 7)) << 3);
            gld16(&kbuf[bi][(wv * 16 + it * 4) * D_], src);
        }
#pragma unroll
        for (int it = 0; it < 4; ++it) {
            const int h = wv * 32 + it * 8 + (lane >> 3);
            const unsigned short* src =
                vg_base + (size_t)h * S_ + kv0 + (((lane & 7) ^ (h & 7)) << 3);
            gld16(&vbuf[bi][(wv * 32 + it * 8) * KVB], src);
        }
    };

    STAGE(0, 0);
    STAGE(1, 1);

    f32x4 acc[8];
#pragma unroll
    for (int ht = 0; ht < 8; ++ht) { f32x4 z = {0.f, 0.f, 0.f, 0.f}; acc[ht] = z; }
    float m_run = -INFINITY, l_run = 0.f;

#pragma unroll 1
    for (int kt = 0; kt < NT; ++kt) {
        const int cur = kt & 1;
        // wait for tile kt's 8 loads (tile kt+1's 8 may stay in flight)
        if (kt + 1 < NT) { asm volatile("s_waitcnt vmcnt(8)" ::: "memory"); }
        else             { asm volatile("s_waitcnt vmcnt(0)" ::: "memory"); }
        __builtin_amdgcn_s_barrier();
        asm volatile("" ::: "memory");

        const unsigned short* kl = kbuf[cur];
        const unsigned short* vl = vbuf[cur];

        // QK^T (swapped): sv[ks] = S^T rows [16ks,16ks+16), lane holds k=16ks+4g+r, q=j
        f32x4 sv0 = {0.f,0.f,0.f,0.f}, sv1 = sv0, sv2 = sv0, sv3 = sv0;
        __builtin_amdgcn_s_setprio(1);
#pragma unroll
        for (int kk = 0; kk < 4; ++kk) {
            const int cs = (((kk * 4 + g) ^ (j & 7)) << 3);
            s16x8 k0 = *(const s16x8*)&kl[(0 * 16 + j) * D_ + cs];
            s16x8 k1 = *(const s16x8*)&kl[(1 * 16 + j) * D_ + cs];
            s16x8 k2 = *(const s16x8*)&kl[(2 * 16 + j) * D_ + cs];
            s16x8 k3 = *(const s16x8*)&kl[(3 * 16 + j) * D_ + cs];
            sv0 = __builtin_amdgcn_mfma_f32_16x16x32_bf16(k0, qf[kk], sv0, 0, 0, 0);
            sv1 = __builtin_amdgcn_mfma_f32_16x16x32_bf16(k1, qf[kk], sv1, 0, 0, 0);
            sv2 = __builtin_amdgcn_mfma_f32_16x16x32_bf16(k2, qf[kk], sv2, 0, 0, 0);
            sv3 = __builtin_amdgcn_mfma_f32_16x16x32_bf16(k3, qf[kk], sv3, 0, 0, 0);
        }
        __builtin_amdgcn_s_setprio(0);

        // per-q max over 64 k
        float mt = fmaxf(
            fmaxf(fmaxf(fmaxf(sv0[0], sv0[1]), fmaxf(sv0[2], sv0[3])),
                  fmaxf(fmaxf(sv1[0], sv1[1]), fmaxf(sv1[2], sv1[3]))),
            fmaxf(fmaxf(fmaxf(sv2[0], sv2[1]), fmaxf(sv2[2], sv2[3])),
                  fmaxf(fmaxf(sv3[0], sv3[1]), fmaxf(sv3[2], sv3[3]))));
        mt = fmaxf(mt, __shfl_xor(mt, 16));
        mt = fmaxf(mt, __shfl_xor(mt, 32));

        // defer-max: rescale only if max grew by more than THR=8
        if (__any(mt > m_run + 8.f)) {
            float mnew = fmaxf(m_run, mt);
            float corr = __expf(m_run - mnew);   // -inf start -> 0
            l_run *= corr;
            float cr0 = __shfl(corr, g * 4 + 0);
            float cr1 = __shfl(corr, g * 4 + 1);
            float cr2 = __shfl(corr, g * 4 + 2);
            float cr3 = __shfl(corr, g * 4 + 3);
#pragma unroll
            for (int ht = 0; ht < 8; ++ht) {
                acc[ht][0] *= cr0; acc[ht][1] *= cr1;
                acc[ht][2] *= cr2; acc[ht][3] *= cr3;
            }
            m_run = mnew;
        }

        float p[16];
#pragma unroll
        for (int r = 0; r < 4; ++r) {
            p[0  + r] = __expf(sv0[r] - m_run);
            p[4  + r] = __expf(sv1[r] - m_run);
            p[8  + r] = __expf(sv2[r] - m_run);
            p[12 + r] = __expf(sv3[r] - m_run);
        }
        float ts = ((p[0] + p[1]) + (p[2] + p[3])) + ((p[4] + p[5]) + (p[6] + p[7]))
                 + ((p[8] + p[9]) + (p[10] + p[11])) + ((p[12] + p[13]) + (p[14] + p[15]));
        ts += __shfl_xor(ts, 16);
        ts += __shfl_xor(ts, 32);
        l_run += ts;

        // redistribute P (S^T slots) into A-fragment layout, two 32-k halves
        unsigned a01 = pack2(p[0],  p[1]),  a23 = pack2(p[2],  p[3]);
        unsigned b01 = pack2(p[4],  p[5]),  b23 = pack2(p[6],  p[7]);
        unsigned c01 = pack2(p[8],  p[9]),  c23 = pack2(p[10], p[11]);
        unsigned d01 = pack2(p[12], p[13]), d23 = pack2(p[14], p[15]);
        const int src1 = ((2 * g) & 3) * 16 + j;
        const int src2 = ((2 * g + 1) & 3) * 16 + j;
        const bool hi = (g >= 2);
        unsigned a1 = __shfl((int)a01, src1), a2 = __shfl((int)a23, src1);
        unsigned a3 = __shfl((int)a01, src2), a4 = __shfl((int)a23, src2);
        unsigned b1 = __shfl((int)b01, src1), b2 = __shfl((int)b23, src1);
        unsigned b3 = __shfl((int)b01, src2), b4 = __shfl((int)b23, src2);
        unsigned e1 = __shfl((int)c01, src1), e2 = __shfl((int)c23, src1);
        unsigned e3 = __shfl((int)c01, src2), e4 = __shfl((int)c23, src2);
        unsigned f1 = __shfl((int)d01, src1), f2 = __shfl((int)d23, src1);
        unsigned f3 = __shfl((int)d01, src2), f4 = __shfl((int)d23, src2);
        union { unsigned u[4]; s16x8 v; } P0, P1;
        P0.u[0] = hi ? b1 : a1; P0.u[1] = hi ? b2 : a2;
        P0.u[2] = hi ? b3 : a3; P0.u[3] = hi ? b4 : a4;
        P1.u[0] = hi ? f1 : e1; P1.u[1] = hi ? f2 : e2;
        P1.u[2] = hi ? f3 : e3; P1.u[3] = hi ? f4 : e4;

        __builtin_amdgcn_s_setprio(1);
#pragma unroll
        for (int ht = 0; ht < 8; ++ht) {
            const int hrow = ht * 16 + j;
            s16x8 vf0 = *(const s16x8*)&vl[hrow * KVB + ((g       ^ (j & 7)) << 3)];
            s16x8 vf1 = *(const s16x8*)&vl[hrow * KVB + (((4 + g) ^ (j & 7)) << 3)];
            acc[ht] = __builtin_amdgcn_mfma_f32_16x16x32_bf16(P0.v, vf0, acc[ht], 0, 0, 0);
            acc[ht] = __builtin_amdgcn_mfma_f32_16x16x32_bf16(P1.v, vf1, acc[ht], 0, 0, 0);
        }
        __builtin_amdgcn_s_setprio(0);

        asm volatile("" ::: "memory");
        __builtin_amdgcn_s_barrier();
        asm volatile("" ::: "memory");
        if (kt + 2 < NT) STAGE(cur, kt + 2);   // overwrite just-consumed buffer
    }

    float linv = 1.0f / l_run;
    float lr0 = __shfl(linv, g * 4 + 0);
    float lr1 = __shfl(linv, g * 4 + 1);
    float lr2 = __shfl(linv, g * 4 + 2);
    float lr3 = __shfl(linv, g * 4 + 3);
#pragma unroll
    for (int ht = 0; ht < 8; ++ht) {
        size_t base = ((size_t)b * S_ + s0 + wv * 16 + g * 4) * D_ + ht * 16 + j;
        out[base         ] = acc[ht][0] * lr0;
        out[base +     D_] = acc[ht][1] * lr1;
        out[base + 2 * D_] = acc[ht][2] * lr2;
        out[base + 3 * D_] = acc[ht][3] * lr3;
    }
}

extern "C" void kernel_launch(void* const* d_in, const int* in_sizes, int n_in,
                              void* d_out, int out_size, void* d_ws, size_t ws_size,
                              hipStream_t stream) {
    const float* x    = (const float*)d_in[0];
    const float* Wq   = (const float*)d_in[1];
    const float* Wk   = (const float*)d_in[2];
    const float* Wv   = (const float*)d_in[3];
    const float* qn_w = (const float*)d_in[4];
    const float* qn_b = (const float*)d_in[5];
    const float* kn_w = (const float*)d_in[6];
    const float* kn_b = (const float*)d_in[7];
    float* out = (float*)d_out;

    const size_t n = (size_t)B_ * S_ * D_;
    unsigned short* qws  = (unsigned short*)d_ws;
    unsigned short* kws  = qws + n;
    unsigned short* vtws = kws + n;

    proj_kernel<<<512, 256, 0, stream>>>(x, Wq, Wk, Wv, qn_w, qn_b, kn_w, kn_b,
                                         qws, kws, vtws);
    attn_kernel<<<512, 256, 0, stream>>>(qws, kws, vtws, out);
}

// Round 3
// 149.025 us; speedup vs baseline: 1.3098x; 1.0724x over previous
//
#include <hip/hip_runtime.h>

#define B_ 8
#define S_ 4096
#define D_ 128
#define KVB 64
#define NT (S_ / KVB)

typedef __attribute__((ext_vector_type(4))) float f32x4;
typedef __attribute__((ext_vector_type(8))) short s16x8;

__device__ __forceinline__ unsigned short f2bf(float f) {
    union { float f; unsigned u; } v; v.f = f;
    unsigned r = (v.u + 0x7fffu + ((v.u >> 16) & 1u)) >> 16;
    return (unsigned short)r;
}

// round-half-up pack of two f32 -> (bf16 lo | bf16 hi<<16); |err| <= 2^-9 rel
__device__ __forceinline__ unsigned pack2(float lo, float hi) {
    union { float f; unsigned u; } a, b; a.f = lo; b.f = hi;
    return ((a.u + 0x8000u) >> 16) | ((b.u + 0x8000u) & 0xffff0000u);
}

__device__ __forceinline__ s16x8 load_cvt8(const float* p) {
    f32x4 a = *(const f32x4*)p;
    f32x4 b = *(const f32x4*)(p + 4);
    s16x8 r;
    r[0] = (short)f2bf(a[0]); r[1] = (short)f2bf(a[1]);
    r[2] = (short)f2bf(a[2]); r[3] = (short)f2bf(a[3]);
    r[4] = (short)f2bf(b[0]); r[5] = (short)f2bf(b[1]);
    r[6] = (short)f2bf(b[2]); r[7] = (short)f2bf(b[3]);
    return r;
}

// async global->LDS, 16B per lane. lds must be wave-uniform base; HW adds lane*16.
__device__ __forceinline__ void gld16(unsigned short* lds, const unsigned short* g) {
    __builtin_amdgcn_global_load_lds(
        (const __attribute__((address_space(1))) unsigned int*)g,
        (__attribute__((address_space(3))) unsigned int*)lds,
        16, 0, 0);
}

// ---------------------------------------------------------------------------
// Kernel 1: q/k/v projections + layernorm(q,k), bf16 outputs, v transposed.
// q is pre-scaled by (1/sqrt(D)) * log2(e) so attention works in exp2 domain.
// ---------------------------------------------------------------------------
__global__ __launch_bounds__(256, 1) void proj_kernel(
    const float* __restrict__ x,  const float* __restrict__ Wq,
    const float* __restrict__ Wk, const float* __restrict__ Wv,
    const float* __restrict__ qn_w, const float* __restrict__ qn_b,
    const float* __restrict__ kn_w, const float* __restrict__ kn_b,
    unsigned short* __restrict__ qo, unsigned short* __restrict__ ko,
    unsigned short* __restrict__ vto)
{
    __shared__ unsigned short wlds[128 * 136];
    __shared__ unsigned short vstage[128 * 72];

    const int tid  = threadIdx.x;
    const int lane = tid & 63;
    const int wv   = tid >> 6;
    const int j    = lane & 15;
    const int g    = lane >> 4;

    const int b    = blockIdx.x >> 6;
    const int sblk = (blockIdx.x & 63) * 64;
    const int srow = sblk + wv * 16;

    const float* xrow = x + ((size_t)b * S_ + srow + j) * D_;
    s16x8 af[4];
#pragma unroll
    for (int kk = 0; kk < 4; ++kk) af[kk] = load_cvt8(xrow + kk * 32 + g * 8);

    const int wrow = tid >> 1;
    const int wcol = (tid & 1) * 64;

#pragma unroll 1
    for (int m = 0; m < 3; ++m) {
        const float* Wm = (m == 0) ? Wq : (m == 1) ? Wk : Wv;
        __syncthreads();
#pragma unroll
        for (int it = 0; it < 8; ++it) {
            int col = wcol + it * 8;
            *(s16x8*)&wlds[wrow * 136 + col] = load_cvt8(Wm + wrow * 128 + col);
        }
        __syncthreads();

        f32x4 acc[8];
#pragma unroll
        for (int ct = 0; ct < 8; ++ct) { f32x4 z = {0.f, 0.f, 0.f, 0.f}; acc[ct] = z; }
#pragma unroll
        for (int ct = 0; ct < 8; ++ct) {
#pragma unroll
            for (int kk = 0; kk < 4; ++kk) {
                s16x8 bf = *(const s16x8*)&wlds[(ct * 16 + j) * 136 + kk * 32 + g * 8];
                acc[ct] = __builtin_amdgcn_mfma_f32_16x16x32_bf16(af[kk], bf, acc[ct], 0, 0, 0);
            }
        }

        if (m < 2) {
            const float* lw = (m == 0) ? qn_w : kn_w;
            const float* lb = (m == 0) ? qn_b : kn_b;
            float sum[4], sq[4];
#pragma unroll
            for (int r = 0; r < 4; ++r) {
                float s1 = 0.f, s2 = 0.f;
#pragma unroll
                for (int ct = 0; ct < 8; ++ct) { float v = acc[ct][r]; s1 += v; s2 += v * v; }
#pragma unroll
                for (int msk = 1; msk < 16; msk <<= 1) {
                    s1 += __shfl_xor(s1, msk);
                    s2 += __shfl_xor(s2, msk);
                }
                sum[r] = s1; sq[r] = s2;
            }
            float gwv[8], gbv[8];
#pragma unroll
            for (int ct = 0; ct < 8; ++ct) { gwv[ct] = lw[ct * 16 + j]; gbv[ct] = lb[ct * 16 + j]; }
            unsigned short* dst = (m == 0) ? qo : ko;
            // q: fold 1/sqrt(128) * log2(e) so scores are in exp2 domain
            const float post = (m == 0) ? 0.12751742361888f : 1.0f;
#pragma unroll
            for (int r = 0; r < 4; ++r) {
                float mean = sum[r] * (1.f / 128.f);
                float var  = sq[r] * (1.f / 128.f) - mean * mean;
                float rstd = rsqrtf(var + 1e-5f);
                size_t rowoff = ((size_t)b * S_ + sblk + wv * 16 + g * 4 + r) * D_;
#pragma unroll
                for (int ct = 0; ct < 8; ++ct) {
                    float val = ((acc[ct][r] - mean) * rstd * gwv[ct] + gbv[ct]) * post;
                    dst[rowoff + ct * 16 + j] = f2bf(val);
                }
            }
        } else {
#pragma unroll
            for (int ct = 0; ct < 8; ++ct) {
#pragma unroll
                for (int r = 0; r < 4; ++r) {
                    vstage[(ct * 16 + j) * 72 + wv * 16 + g * 4 + r] = f2bf(acc[ct][r]);
                }
            }
            __syncthreads();
            int h  = tid >> 1;
            int cb = (tid & 1) * 32;
#pragma unroll
            for (int c = 0; c < 4; ++c) {
                *(s16x8*)(vto + ((size_t)b * D_ + h) * S_ + sblk + cb + c * 8) =
                    *(const s16x8*)&vstage[h * 72 + cb + c * 8];
            }
        }
    }
}

// ---------------------------------------------------------------------------
// Kernel 2: flash attention, zero-shuffle softmax.
// QK^T MFMAs consume permuted K-rows pi_ks(j) = 8*(j>>2)+(j&3)+4*(ks&1)+32*(ks>>1)
// so lane (j,g) is born holding P[q=j][k=8g+...] — already the PV A-fragment.
// Row-sum l comes from an extra MFMA against a ones fragment (same layout as acc).
// K LDS swizzle: slot = colblk ^ fK(row), fK(row) = (row&3)|(((row>>3)&1)<<2)
// (keeps the permuted-row reads 8-way bank-spread).
// ---------------------------------------------------------------------------
__global__ __launch_bounds__(256, 1) void attn_kernel(
    const unsigned short* __restrict__ qb, const unsigned short* __restrict__ kb,
    const unsigned short* __restrict__ vtb, float* __restrict__ out)
{
    __shared__ unsigned short kbuf[2][KVB * D_];
    __shared__ unsigned short vbuf[2][D_ * KVB];

    const int tid  = threadIdx.x;
    const int lane = tid & 63;
    const int wv   = tid >> 6;
    const int j    = lane & 15;
    const int g    = lane >> 4;

    const int b  = blockIdx.x >> 6;
    const int s0 = (blockIdx.x & 63) * 64;

    // Q fragments (rows s0 + wv*16 + j); q pre-scaled by 1/sqrt(D)*log2e
    const unsigned short* qrow = qb + ((size_t)b * S_ + s0 + wv * 16 + j) * D_;
    s16x8 qf[4];
#pragma unroll
    for (int kk = 0; kk < 4; ++kk) qf[kk] = *(const s16x8*)(qrow + kk * 32 + g * 8);

    const unsigned short* kg_base = kb  + (size_t)b * S_ * D_;
    const unsigned short* vg_base = vtb + (size_t)b * D_ * S_;

    auto STAGE = [&](int bi, int kt) {
        const int kv0 = kt * KVB;
#pragma unroll
        for (int it = 0; it < 4; ++it) {
            const int row = wv * 16 + it * 4 + (lane >> 4);
            const int fk  = (row & 3) | (((row >> 3) & 1) << 2);
            const unsigned short* src =
                kg_base + (size_t)(kv0 + row) * D_ + (((lane & 15) ^ fk) << 3);
            gld16(&kbuf[bi][(wv * 16 + it * 4) * D_], src);
        }
#pragma unroll
        for (int it = 0; it < 4; ++it) {
            const int h = wv * 32 + it * 8 + (lane >> 3);
            const unsigned short* src =
                vg_base + (size_t)h * S_ + kv0 + (((lane & 7) ^ (h & 7)) << 3);
            gld16(&vbuf[bi][(wv * 32 + it * 8) * KVB], src);
        }
    };

    STAGE(0, 0);
    STAGE(1, 1);

    f32x4 acc[8];
#pragma unroll
    for (int ht = 0; ht < 8; ++ht) { f32x4 z = {0.f, 0.f, 0.f, 0.f}; acc[ht] = z; }
    f32x4 acc_l = {0.f, 0.f, 0.f, 0.f};
    float m_run = -INFINITY;

    // ones B-fragment (bf16 1.0 = 0x3F80) for the row-sum MFMA
    s16x8 ones;
#pragma unroll
    for (int e = 0; e < 8; ++e) ones[e] = (short)0x3F80;

    // loop-invariant K-read addressing
    const int fKj  = (j & 3) | (((j >> 2) & 1) << 2);
    const int prow = 8 * (j >> 2) + (j & 3);    // pi_0(j); +4 / +32 / +36 for ks=1..3

#pragma unroll 1
    for (int kt = 0; kt < NT; ++kt) {
        const int cur = kt & 1;
        if (kt + 1 < NT) { asm volatile("s_waitcnt vmcnt(8)" ::: "memory"); }
        else             { asm volatile("s_waitcnt vmcnt(0)" ::: "memory"); }
        __builtin_amdgcn_s_barrier();
        asm volatile("" ::: "memory");

        const unsigned short* kl = kbuf[cur];
        const unsigned short* vl = vbuf[cur];

        // QK^T with permuted rows: sv_ks[r] = S[q=j][k = 8g + r + 4*(ks&1) + 32*(ks>>1)]
        f32x4 sv0 = {0.f,0.f,0.f,0.f}, sv1 = sv0, sv2 = sv0, sv3 = sv0;
        __builtin_amdgcn_s_setprio(1);
#pragma unroll
        for (int kk = 0; kk < 4; ++kk) {
            const int cs = (((kk * 4 + g) ^ fKj) << 3);
            s16x8 k0 = *(const s16x8*)&kl[(prow     ) * D_ + cs];
            s16x8 k1 = *(const s16x8*)&kl[(prow +  4) * D_ + cs];
            s16x8 k2 = *(const s16x8*)&kl[(prow + 32) * D_ + cs];
            s16x8 k3 = *(const s16x8*)&kl[(prow + 36) * D_ + cs];
            sv0 = __builtin_amdgcn_mfma_f32_16x16x32_bf16(k0, qf[kk], sv0, 0, 0, 0);
            sv1 = __builtin_amdgcn_mfma_f32_16x16x32_bf16(k1, qf[kk], sv1, 0, 0, 0);
            sv2 = __builtin_amdgcn_mfma_f32_16x16x32_bf16(k2, qf[kk], sv2, 0, 0, 0);
            sv3 = __builtin_amdgcn_mfma_f32_16x16x32_bf16(k3, qf[kk], sv3, 0, 0, 0);
        }
        __builtin_amdgcn_s_setprio(0);

        // per-q (=j) max over 64 k (in log2 domain)
        float mt = fmaxf(
            fmaxf(fmaxf(fmaxf(sv0[0], sv0[1]), fmaxf(sv0[2], sv0[3])),
                  fmaxf(fmaxf(sv1[0], sv1[1]), fmaxf(sv1[2], sv1[3]))),
            fmaxf(fmaxf(fmaxf(sv2[0], sv2[1]), fmaxf(sv2[2], sv2[3])),
                  fmaxf(fmaxf(sv3[0], sv3[1]), fmaxf(sv3[2], sv3[3]))));
        mt = fmaxf(mt, __shfl_xor(mt, 16));
        mt = fmaxf(mt, __shfl_xor(mt, 32));

        // defer-max: rescale only if max grew by more than 11.5 (= 8 nats)
        if (__any(mt > m_run + 11.5f)) {
            float mnew = fmaxf(m_run, mt);
            float corr = exp2f(m_run - mnew);    // -inf start -> 0
            float cr0 = __shfl(corr, g * 4 + 0);
            float cr1 = __shfl(corr, g * 4 + 1);
            float cr2 = __shfl(corr, g * 4 + 2);
            float cr3 = __shfl(corr, g * 4 + 3);
#pragma unroll
            for (int ht = 0; ht < 8; ++ht) {
                acc[ht][0] *= cr0; acc[ht][1] *= cr1;
                acc[ht][2] *= cr2; acc[ht][3] *= cr3;
            }
            acc_l[0] *= cr0; acc_l[1] *= cr1; acc_l[2] *= cr2; acc_l[3] *= cr3;
            m_run = mnew;
        }

        float p0[4], p1[4], p2[4], p3[4];
#pragma unroll
        for (int r = 0; r < 4; ++r) {
            p0[r] = exp2f(sv0[r] - m_run);
            p1[r] = exp2f(sv1[r] - m_run);
            p2[r] = exp2f(sv2[r] - m_run);
            p3[r] = exp2f(sv3[r] - m_run);
        }

        // P fragments: already in A-fragment layout, no cross-lane ops
        union { unsigned u[4]; s16x8 v; } P0, P1;
        P0.u[0] = pack2(p0[0], p0[1]); P0.u[1] = pack2(p0[2], p0[3]);
        P0.u[2] = pack2(p1[0], p1[1]); P0.u[3] = pack2(p1[2], p1[3]);
        P1.u[0] = pack2(p2[0], p2[1]); P1.u[1] = pack2(p2[2], p2[3]);
        P1.u[2] = pack2(p3[0], p3[1]); P1.u[3] = pack2(p3[2], p3[3]);

        __builtin_amdgcn_s_setprio(1);
        // row-sum l via ones-MFMA (same per-lane layout as acc)
        acc_l = __builtin_amdgcn_mfma_f32_16x16x32_bf16(P0.v, ones, acc_l, 0, 0, 0);
        acc_l = __builtin_amdgcn_mfma_f32_16x16x32_bf16(P1.v, ones, acc_l, 0, 0, 0);
#pragma unroll
        for (int ht = 0; ht < 8; ++ht) {
            const int hrow = ht * 16 + j;
            s16x8 vf0 = *(const s16x8*)&vl[hrow * KVB + ((g       ^ (j & 7)) << 3)];
            s16x8 vf1 = *(const s16x8*)&vl[hrow * KVB + (((4 + g) ^ (j & 7)) << 3)];
            acc[ht] = __builtin_amdgcn_mfma_f32_16x16x32_bf16(P0.v, vf0, acc[ht], 0, 0, 0);
            acc[ht] = __builtin_amdgcn_mfma_f32_16x16x32_bf16(P1.v, vf1, acc[ht], 0, 0, 0);
        }
        __builtin_amdgcn_s_setprio(0);

        asm volatile("" ::: "memory");
        __builtin_amdgcn_s_barrier();
        asm volatile("" ::: "memory");
        if (kt + 2 < NT) STAGE(cur, kt + 2);
    }

    const float lr0 = 1.0f / acc_l[0];
    const float lr1 = 1.0f / acc_l[1];
    const float lr2 = 1.0f / acc_l[2];
    const float lr3 = 1.0f / acc_l[3];
#pragma unroll
    for (int ht = 0; ht < 8; ++ht) {
        size_t base = ((size_t)b * S_ + s0 + wv * 16 + g * 4) * D_ + ht * 16 + j;
        out[base         ] = acc[ht][0] * lr0;
        out[base +     D_] = acc[ht][1] * lr1;
        out[base + 2 * D_] = acc[ht][2] * lr2;
        out[base + 3 * D_] = acc[ht][3] * lr3;
    }
}

extern "C" void kernel_launch(void* const* d_in, const int* in_sizes, int n_in,
                              void* d_out, int out_size, void* d_ws, size_t ws_size,
                              hipStream_t stream) {
    const float* x    = (const float*)d_in[0];
    const float* Wq   = (const float*)d_in[1];
    const float* Wk   = (const float*)d_in[2];
    const float* Wv   = (const float*)d_in[3];
    const float* qn_w = (const float*)d_in[4];
    const float* qn_b = (const float*)d_in[5];
    const float* kn_w = (const float*)d_in[6];
    const float* kn_b = (const float*)d_in[7];
    float* out = (float*)d_out;

    const size_t n = (size_t)B_ * S_ * D_;
    unsigned short* qws  = (unsigned short*)d_ws;
    unsigned short* kws  = qws + n;
    unsigned short* vtws = kws + n;

    proj_kernel<<<512, 256, 0, stream>>>(x, Wq, Wk, Wv, qn_w, qn_b, kn_w, kn_b,
                                         qws, kws, vtws);
    attn_kernel<<<512, 256, 0, stream>>>(qws, kws, vtws, out);
}